// Round 1
// baseline (2688.439 us; speedup 1.0000x reference)
//
#include <hip/hip_runtime.h>
#include <math.h>

#define NTHREADS 256
#define HID 256
#define MS 9          // samples per block
#define LSTR 68       // LDS stride (floats) per unit: 64 rows + pad, 16B-aligned

// States per sample, each a 256-vector at hidden layers:
//   row = state*MS + m, state: 0=H, 1..3 = t_k, 4..6 = r_k, row 63 = zero pad.
__global__ __launch_bounds__(NTHREADS, 2)
void pinn_fused(const float* __restrict__ X,
                const float* __restrict__ W0, const float* __restrict__ b0,
                const float* __restrict__ W1, const float* __restrict__ b1,
                const float* __restrict__ W2, const float* __restrict__ b2,
                const float* __restrict__ W3, const float* __restrict__ b3,
                const float* __restrict__ W4, const float* __restrict__ b4,
                const float* __restrict__ lb, const float* __restrict__ ub,
                float* __restrict__ out, int N)
{
    __shared__ float buf[HID * LSTR];   // [unit k][row], transposed for GEMM A-reads
    __shared__ float red[64 * 8];       // final-layer reduction scratch

    const int t  = threadIdx.x;
    const int s0 = blockIdx.x * MS;

    float lbv[3], cv[3];
    #pragma unroll
    for (int k = 0; k < 3; ++k) {
        lbv[k] = lb[k];
        cv[k]  = 2.0f / (ub[k] - lbv[k]);
    }

    // ---------------- layer 0: inputs -> first hidden states ----------------
    for (int p = t; p < HID * MS; p += NTHREADS) {
        const int j = p / MS, m = p % MS;
        const int n = s0 + m;
        float x0 = 0.f, x1 = 0.f, x2 = 0.f;
        if (n < N) { x0 = X[n*3+0]; x1 = X[n*3+1]; x2 = X[n*3+2]; }
        const float h0 = cv[0]*(x0 - lbv[0]) - 1.0f;
        const float h1 = cv[1]*(x1 - lbv[1]) - 1.0f;
        const float h2 = cv[2]*(x2 - lbv[2]) - 1.0f;
        const float w0j = W0[0*HID + j];
        const float w1j = W0[1*HID + j];
        const float w2j = W0[2*HID + j];
        const float zH  = h0*w0j + h1*w1j + h2*w2j + b0[j];
        const float zt0 = cv[0]*w0j;     // tangent k hits only input-row k of W0
        const float zt1 = cv[1]*w1j;
        const float zt2 = cv[2]*w2j;
        const float sz  = zt0 + zt1 + zt2;
        const float h   = tanhf(zH);
        const float dd  = 1.0f - h*h;
        const float q   = -2.0f * h * sz;
        float* bj = &buf[j * LSTR];
        bj[0*MS + m] = h;
        bj[1*MS + m] = dd * zt0;
        bj[2*MS + m] = dd * zt1;
        bj[3*MS + m] = dd * zt2;
        bj[4*MS + m] = dd * (q * zt0);   // zr = 0 at input
        bj[5*MS + m] = dd * (q * zt1);
        bj[6*MS + m] = dd * (q * zt2);
    }
    buf[t * LSTR + 63] = 0.0f;           // zero the pad row for every unit
    __syncthreads();

    // ---------------- hidden layers 1..3 ----------------
    const float* Wl[3] = {W1, W2, W3};
    const float* bl[3] = {b1, b2, b3};
    const int rg = t >> 4;   // row group: rows rg*4 .. rg*4+3   (16 groups)
    const int cg = t & 15;   // col group: cols cg*16 .. cg*16+15 (16 groups)

    for (int l = 0; l < 3; ++l) {
        const float* __restrict__ W = Wl[l] + cg * 16;
        float acc[4][16];
        #pragma unroll
        for (int r = 0; r < 4; ++r) {
            #pragma unroll
            for (int c = 0; c < 16; ++c) acc[r][c] = 0.0f;
        }

        // C[64 x 256] = A[64 x 256] * W[256 x 256], A in LDS (transposed), W via L1/L2
        #pragma unroll 4
        for (int k = 0; k < HID; ++k) {
            const float4 a = *(const float4*)&buf[k*LSTR + rg*4];
            const float4* wv = (const float4*)(W + (size_t)k * HID);
            const float4 w0 = wv[0], w1 = wv[1], w2 = wv[2], w3 = wv[3];
            const float av[4] = {a.x, a.y, a.z, a.w};
            #pragma unroll
            for (int r = 0; r < 4; ++r) {
                acc[r][0]  += av[r] * w0.x;
                acc[r][1]  += av[r] * w0.y;
                acc[r][2]  += av[r] * w0.z;
                acc[r][3]  += av[r] * w0.w;
                acc[r][4]  += av[r] * w1.x;
                acc[r][5]  += av[r] * w1.y;
                acc[r][6]  += av[r] * w1.z;
                acc[r][7]  += av[r] * w1.w;
                acc[r][8]  += av[r] * w2.x;
                acc[r][9]  += av[r] * w2.y;
                acc[r][10] += av[r] * w2.z;
                acc[r][11] += av[r] * w2.w;
                acc[r][12] += av[r] * w3.x;
                acc[r][13] += av[r] * w3.y;
                acc[r][14] += av[r] * w3.z;
                acc[r][15] += av[r] * w3.w;
            }
        }
        __syncthreads();   // all A-reads complete before overwrite

        // write z back into buf (same transposed layout)
        #pragma unroll
        for (int i = 0; i < 16; ++i) {
            const float4 v = make_float4(acc[0][i], acc[1][i], acc[2][i], acc[3][i]);
            *(float4*)&buf[(cg*16 + i)*LSTR + rg*4] = v;
        }
        __syncthreads();

        // nonlinearity coupling, in place (each (unit j, sample m) owned by one thread)
        const float* __restrict__ bb = bl[l];
        for (int p = t; p < HID * MS; p += NTHREADS) {
            const int j = p / MS, m = p % MS;
            float* bj = &buf[j * LSTR];
            const float zH  = bj[0*MS + m] + bb[j];
            const float zt0 = bj[1*MS + m];
            const float zt1 = bj[2*MS + m];
            const float zt2 = bj[3*MS + m];
            const float zr0 = bj[4*MS + m];
            const float zr1 = bj[5*MS + m];
            const float zr2 = bj[6*MS + m];
            const float sz  = zt0 + zt1 + zt2;     // s = t0+t1+t2 (linearity)
            const float h   = tanhf(zH);
            const float dd  = 1.0f - h*h;
            const float q   = -2.0f * h * sz;
            bj[0*MS + m] = h;
            bj[1*MS + m] = dd * zt0;
            bj[2*MS + m] = dd * zt1;
            bj[3*MS + m] = dd * zt2;
            bj[4*MS + m] = dd * (zr0 + q*zt0);
            bj[5*MS + m] = dd * (zr1 + q*zt1);
            bj[6*MS + m] = dd * (zr2 + q*zt2);
        }
        __syncthreads();
    }

    // ---------------- final linear layer (256 -> 2) ----------------
    {
        const int r  = t & 63;    // state row
        const int kq = t >> 6;    // K-quarter
        float a0 = 0.f, a1 = 0.f;
        const int k0 = kq * 64;
        #pragma unroll 8
        for (int k = k0; k < k0 + 64; ++k) {
            const float a  = buf[k*LSTR + r];
            const float2 w = *(const float2*)&W4[k*2];
            a0 += a * w.x;
            a1 += a * w.y;
        }
        red[r*8 + kq*2 + 0] = a0;
        red[r*8 + kq*2 + 1] = a1;
    }
    __syncthreads();
    if (t < 126) {
        const int r = t >> 1, i = t & 1;   // r < 63
        const float v = red[r*8 + 0 + i] + red[r*8 + 2 + i]
                      + red[r*8 + 4 + i] + red[r*8 + 6 + i];
        const int s = r / MS, m = r % MS;
        const int n = s0 + m;
        if (n < N) {
            const size_t N2 = (size_t)N * 2, N3 = (size_t)N * 3;
            if (s == 0)      out[(size_t)n*2 + i] = v + b4[i];
            else if (s <= 3) out[N2 + (size_t)i*N3 + (size_t)n*3 + (s-1)] = v;
            else             out[N2 + 2*N3 + (size_t)i*N3 + (size_t)n*3 + (s-4)] = v;
        }
    }
}

extern "C" void kernel_launch(void* const* d_in, const int* in_sizes, int n_in,
                              void* d_out, int out_size, void* d_ws, size_t ws_size,
                              hipStream_t stream) {
    const float* X  = (const float*)d_in[0];
    const float* W0 = (const float*)d_in[1];
    const float* b0 = (const float*)d_in[2];
    const float* W1 = (const float*)d_in[3];
    const float* b1 = (const float*)d_in[4];
    const float* W2 = (const float*)d_in[5];
    const float* b2 = (const float*)d_in[6];
    const float* W3 = (const float*)d_in[7];
    const float* b3 = (const float*)d_in[8];
    const float* W4 = (const float*)d_in[9];
    const float* b4 = (const float*)d_in[10];
    const float* lb = (const float*)d_in[11];
    const float* ub = (const float*)d_in[12];
    float* out = (float*)d_out;

    const int N = in_sizes[0] / 3;
    const int grid = (N + MS - 1) / MS;
    pinn_fused<<<grid, NTHREADS, 0, stream>>>(
        X, W0, b0, W1, b1, W2, b2, W3, b3, W4, b4, lb, ub, out, N);
}

// Round 2
// 451.407 us; speedup vs baseline: 5.9557x; 5.9557x over previous
//
#include <hip/hip_runtime.h>
#include <math.h>

typedef __bf16 bf16x8 __attribute__((ext_vector_type(8)));
typedef float  f32x4  __attribute__((ext_vector_type(4)));

#define MSAMP 8       // samples per block
#define ZSTR  260     // zbuf row stride (floats), 16B-aligned, 260%32=4 breaks bank stride

// W swizzle (bf16 elems): off(l,kt,nt,split,lane,j) =
//   (((l*8+kt)*16+nt)*2+split)*512 + lane*8 + j      ; per-l stride 131072 elems
// One B-fragment (16x16x32): lane holds B[k=kt*32+(lane>>4)*8+j][n=nt*16+(lane&15)]
__global__ void prep_w(const float* __restrict__ W1, const float* __restrict__ W2,
                       const float* __restrict__ W3, __bf16* __restrict__ wsw) {
    const int tid = blockIdx.x * 256 + threadIdx.x;      // 3*8*16*64*8 = 196608
    if (tid >= 3 * 8 * 16 * 64 * 8) return;
    const int j    = tid & 7;
    const int lane = (tid >> 3) & 63;
    const int nt   = (tid >> 9) & 15;
    const int kt   = (tid >> 13) & 7;
    const int l    = tid >> 16;
    const float* W = (l == 0) ? W1 : (l == 1) ? W2 : W3;
    const int k = kt * 32 + (lane >> 4) * 8 + j;
    const int n = nt * 16 + (lane & 15);
    const float w = W[k * 256 + n];
    const __bf16 hi = (__bf16)w;
    const __bf16 lo = (__bf16)(w - (float)hi);
    const size_t base = ((size_t)((l * 8 + kt) * 16 + nt) * 2) * 512 + lane * 8 + j;
    wsw[base]       = hi;
    wsw[base + 512] = lo;
}

// rows: row = state*8 + m  (state 0=H, 1..3=t_k, 4..6=r_k), rows 56..63 zero pad
__global__ __launch_bounds__(256, 1)
void pinn_mfma(const float* __restrict__ X,
               const float* __restrict__ W0, const float* __restrict__ b0,
               const float* __restrict__ b1, const float* __restrict__ b2,
               const float* __restrict__ b3,
               const float* __restrict__ W4, const float* __restrict__ b4,
               const float* __restrict__ lb, const float* __restrict__ ub,
               const __bf16* __restrict__ wsw,
               float* __restrict__ out, int N)
{
    // A-frag LDS: [kt 0..7][mt 0..3][lane 0..63][j 0..7], contiguous 16B per lane
    __shared__ __attribute__((aligned(16))) __bf16 Ahi[8 * 4 * 64 * 8];
    __shared__ __attribute__((aligned(16))) __bf16 Alo[8 * 4 * 64 * 8];
    __shared__ __attribute__((aligned(16))) float  zbuf[64 * ZSTR];
    __shared__ __attribute__((aligned(16))) float  red[64 * 8];

    const int t  = threadIdx.x;
    const int s0 = blockIdx.x * MSAMP;
    const int jg = t >> 3;      // unit group: units jg*8 .. jg*8+7
    const int m  = t & 7;       // sample within block
    const int kt0 = jg >> 2, lq0 = jg & 3;   // frag coords for this unit group

    float lbv[3], cv[3];
    #pragma unroll
    for (int k = 0; k < 3; ++k) { lbv[k] = lb[k]; cv[k] = 2.0f / (ub[k] - lbv[k]); }

    // ---------------- layer 0: inputs -> first hidden states (A frags) ----------------
    {
        const int n = s0 + m;
        float x0 = 0.f, x1 = 0.f, x2 = 0.f;
        if (n < N) { x0 = X[n*3+0]; x1 = X[n*3+1]; x2 = X[n*3+2]; }
        const float h0 = cv[0]*(x0 - lbv[0]) - 1.0f;
        const float h1 = cv[1]*(x1 - lbv[1]) - 1.0f;
        const float h2 = cv[2]*(x2 - lbv[2]) - 1.0f;

        float w0v[8], w1v[8], w2v[8], bv[8];
        *(f32x4*)&w0v[0] = *(const f32x4*)&W0[0*256 + jg*8];
        *(f32x4*)&w0v[4] = *(const f32x4*)&W0[0*256 + jg*8 + 4];
        *(f32x4*)&w1v[0] = *(const f32x4*)&W0[1*256 + jg*8];
        *(f32x4*)&w1v[4] = *(const f32x4*)&W0[1*256 + jg*8 + 4];
        *(f32x4*)&w2v[0] = *(const f32x4*)&W0[2*256 + jg*8];
        *(f32x4*)&w2v[4] = *(const f32x4*)&W0[2*256 + jg*8 + 4];
        *(f32x4*)&bv[0]  = *(const f32x4*)&b0[jg*8];
        *(f32x4*)&bv[4]  = *(const f32x4*)&b0[jg*8 + 4];

        float st[7][8];
        #pragma unroll
        for (int jj = 0; jj < 8; ++jj) {
            const float zH  = h0*w0v[jj] + h1*w1v[jj] + h2*w2v[jj] + bv[jj];
            const float zt0 = cv[0]*w0v[jj];
            const float zt1 = cv[1]*w1v[jj];
            const float zt2 = cv[2]*w2v[jj];
            const float h   = tanhf(zH);
            const float dd  = 1.0f - h*h;
            const float q   = -2.0f * h * (zt0 + zt1 + zt2);
            st[0][jj] = h;
            st[1][jj] = dd * zt0; st[2][jj] = dd * zt1; st[3][jj] = dd * zt2;
            st[4][jj] = dd * (q*zt0); st[5][jj] = dd * (q*zt1); st[6][jj] = dd * (q*zt2);
        }
        #pragma unroll
        for (int s = 0; s < 7; ++s) {
            const int row = s*8 + m;
            const int off = ((kt0*4 + (row>>4))*64 + lq0*16 + (row & 15)) * 8;
            bf16x8 vh, vl;
            #pragma unroll
            for (int jj = 0; jj < 8; ++jj) {
                vh[jj] = (__bf16)st[s][jj];
                vl[jj] = (__bf16)(st[s][jj] - (float)vh[jj]);
            }
            *(bf16x8*)&Ahi[off] = vh;
            *(bf16x8*)&Alo[off] = vl;
        }
        // zero the pad rows 56..63 (mt=3, row&15 in 8..15) for every kt/lane-quad
        const int ktz = t >> 5, lqz = (t >> 3) & 3, rz = 8 + (t & 7);
        const int offz = ((ktz*4 + 3)*64 + lqz*16 + rz) * 8;
        bf16x8 zv = {};
        *(bf16x8*)&Ahi[offz] = zv;
        *(bf16x8*)&Alo[offz] = zv;
    }
    __syncthreads();

    // ---------------- hidden layers: GEMM (MFMA) + coupling ----------------
    const int wv = t >> 6, lane = t & 63;

    #pragma unroll 1
    for (int l = 0; l < 3; ++l) {
        const __bf16* __restrict__ Wb = wsw + (size_t)l * 131072;

        f32x4 acc[4][4];   // [mt][ntl]
        #pragma unroll
        for (int a = 0; a < 4; ++a)
            #pragma unroll
            for (int b = 0; b < 4; ++b) acc[a][b] = (f32x4){0.f, 0.f, 0.f, 0.f};

        #pragma unroll
        for (int kt = 0; kt < 8; ++kt) {
            bf16x8 ah[4], al[4];
            #pragma unroll
            for (int mt = 0; mt < 4; ++mt) {
                const int off = ((kt*4 + mt)*64 + lane) * 8;
                ah[mt] = *(const bf16x8*)&Ahi[off];
                al[mt] = *(const bf16x8*)&Alo[off];
            }
            #pragma unroll
            for (int ntl = 0; ntl < 4; ++ntl) {
                const int nt = wv*4 + ntl;
                const bf16x8 bh = *(const bf16x8*)&Wb[(size_t)((kt*16 + nt)*2 + 0)*512 + lane*8];
                const bf16x8 bl_= *(const bf16x8*)&Wb[(size_t)((kt*16 + nt)*2 + 1)*512 + lane*8];
                #pragma unroll
                for (int mt = 0; mt < 4; ++mt) {
                    f32x4 c = acc[mt][ntl];
                    c = __builtin_amdgcn_mfma_f32_16x16x32_bf16(al[mt], bh,  c, 0, 0, 0);
                    c = __builtin_amdgcn_mfma_f32_16x16x32_bf16(ah[mt], bl_, c, 0, 0, 0);
                    c = __builtin_amdgcn_mfma_f32_16x16x32_bf16(ah[mt], bh,  c, 0, 0, 0);
                    acc[mt][ntl] = c;
                }
            }
        }

        // C frags -> zbuf (row-major [row][col]); C: row=mt*16+(lane>>4)*4+reg, col=nt*16+(lane&15)
        #pragma unroll
        for (int mt = 0; mt < 4; ++mt) {
            const int row0 = mt*16 + (lane >> 4)*4;
            #pragma unroll
            for (int ntl = 0; ntl < 4; ++ntl) {
                const int col = (wv*4 + ntl)*16 + (lane & 15);
                #pragma unroll
                for (int reg = 0; reg < 4; ++reg)
                    zbuf[(row0 + reg)*ZSTR + col] = acc[mt][ntl][reg];
            }
        }
        __syncthreads();

        // coupling: thread owns (unit group jg, sample m); all in registers
        {
            const float* __restrict__ bb = (l == 0) ? b1 : (l == 1) ? b2 : b3;
            float bvv[8];
            *(f32x4*)&bvv[0] = *(const f32x4*)&bb[jg*8];
            *(f32x4*)&bvv[4] = *(const f32x4*)&bb[jg*8 + 4];

            float z[7][8];
            #pragma unroll
            for (int s = 0; s < 7; ++s) {
                *(f32x4*)&z[s][0] = *(const f32x4*)&zbuf[(s*8 + m)*ZSTR + jg*8];
                *(f32x4*)&z[s][4] = *(const f32x4*)&zbuf[(s*8 + m)*ZSTR + jg*8 + 4];
            }
            float stt[7][8];
            #pragma unroll
            for (int jj = 0; jj < 8; ++jj) {
                const float zH  = z[0][jj] + bvv[jj];
                const float zt0 = z[1][jj], zt1 = z[2][jj], zt2 = z[3][jj];
                const float zr0 = z[4][jj], zr1 = z[5][jj], zr2 = z[6][jj];
                const float h   = tanhf(zH);
                const float dd  = 1.0f - h*h;
                const float q   = -2.0f * h * (zt0 + zt1 + zt2);
                stt[0][jj] = h;
                stt[1][jj] = dd * zt0; stt[2][jj] = dd * zt1; stt[3][jj] = dd * zt2;
                stt[4][jj] = dd * (zr0 + q*zt0);
                stt[5][jj] = dd * (zr1 + q*zt1);
                stt[6][jj] = dd * (zr2 + q*zt2);
            }
            #pragma unroll
            for (int s = 0; s < 7; ++s) {
                const int row = s*8 + m;
                const int off = ((kt0*4 + (row>>4))*64 + lq0*16 + (row & 15)) * 8;
                bf16x8 vh, vl;
                #pragma unroll
                for (int jj = 0; jj < 8; ++jj) {
                    vh[jj] = (__bf16)stt[s][jj];
                    vl[jj] = (__bf16)(stt[s][jj] - (float)vh[jj]);
                }
                *(bf16x8*)&Ahi[off] = vh;
                *(bf16x8*)&Alo[off] = vl;
                if (l == 2) {   // final coupled states needed in fp32 for the last layer
                    *(f32x4*)&zbuf[row*ZSTR + jg*8]     = *(const f32x4*)&stt[s][0];
                    *(f32x4*)&zbuf[row*ZSTR + jg*8 + 4] = *(const f32x4*)&stt[s][4];
                }
            }
        }
        __syncthreads();
    }

    // ---------------- final linear layer (256 -> 2) ----------------
    {
        const int r = t & 63, kq = t >> 6;
        float a0 = 0.f, a1 = 0.f;
        #pragma unroll
        for (int kk = 0; kk < 16; ++kk) {
            const f32x4 a = *(const f32x4*)&zbuf[r*ZSTR + kq*64 + kk*4];
            #pragma unroll
            for (int c = 0; c < 4; ++c) {
                const float2 w = *(const float2*)&W4[(kq*64 + kk*4 + c)*2];
                a0 += a[c] * w.x;
                a1 += a[c] * w.y;
            }
        }
        red[r*8 + kq*2 + 0] = a0;
        red[r*8 + kq*2 + 1] = a1;
    }
    __syncthreads();
    if (t < 112) {
        const int r = t >> 1, i = t & 1;           // r = state*8+m, 0..55
        const float v = red[r*8 + 0 + i] + red[r*8 + 2 + i]
                      + red[r*8 + 4 + i] + red[r*8 + 6 + i];
        const int s = r >> 3, mm = r & 7;
        const int n = s0 + mm;
        if (n < N) {
            const size_t N2 = (size_t)N * 2, N3 = (size_t)N * 3;
            if (s == 0)      out[(size_t)n*2 + i] = v + b4[i];
            else if (s <= 3) out[N2 + (size_t)i*N3 + (size_t)n*3 + (s-1)] = v;
            else             out[N2 + 2*N3 + (size_t)i*N3 + (size_t)n*3 + (s-4)] = v;
        }
    }
}

extern "C" void kernel_launch(void* const* d_in, const int* in_sizes, int n_in,
                              void* d_out, int out_size, void* d_ws, size_t ws_size,
                              hipStream_t stream) {
    const float* X  = (const float*)d_in[0];
    const float* W0 = (const float*)d_in[1];
    const float* b0 = (const float*)d_in[2];
    const float* W1 = (const float*)d_in[3];
    const float* b1 = (const float*)d_in[4];
    const float* W2 = (const float*)d_in[5];
    const float* b2 = (const float*)d_in[6];
    const float* W3 = (const float*)d_in[7];
    const float* b3 = (const float*)d_in[8];
    const float* W4 = (const float*)d_in[9];
    const float* b4 = (const float*)d_in[10];
    const float* lb = (const float*)d_in[11];
    const float* ub = (const float*)d_in[12];
    float* out = (float*)d_out;
    __bf16* wsw = (__bf16*)d_ws;   // needs 768 KB

    const int N = in_sizes[0] / 3;

    prep_w<<<768, 256, 0, stream>>>(W1, W2, W3, wsw);

    const int grid = (N + MSAMP - 1) / MSAMP;
    pinn_mfma<<<grid, 256, 0, stream>>>(X, W0, b0, b1, b2, b3, W4, b4, lb, ub,
                                        wsw, out, N);
}

// Round 4
// 333.092 us; speedup vs baseline: 8.0712x; 1.3552x over previous
//
#include <hip/hip_runtime.h>
#include <math.h>

typedef __bf16 bf16x8 __attribute__((ext_vector_type(8)));
typedef float  f32x4  __attribute__((ext_vector_type(4)));
// may_alias views for the unioned LDS region (A-frags <-> zbuf) — kills strict-aliasing UB
typedef bf16x8 bf16x8_a __attribute__((may_alias));
typedef f32x4  f32x4_a  __attribute__((may_alias));
typedef float  f32_a    __attribute__((may_alias));

#define MSAMP 8       // samples per block
#define ZSTR  260     // zbuf row stride (floats), 16B-aligned

// W swizzle (bf16 elems): off(l,kt,nt,split,lane,j) =
//   (((l*8+kt)*16+nt)*2+split)*512 + lane*8 + j      ; per-l stride 131072 elems
// One B-fragment (16x16x32): lane holds B[k=kt*32+(lane>>4)*8+j][n=nt*16+(lane&15)]
__global__ void prep_w(const float* __restrict__ W1, const float* __restrict__ W2,
                       const float* __restrict__ W3, __bf16* __restrict__ wsw) {
    const int tid = blockIdx.x * 256 + threadIdx.x;      // 3*8*16*64*8 = 196608
    if (tid >= 3 * 8 * 16 * 64 * 8) return;
    const int j    = tid & 7;
    const int lane = (tid >> 3) & 63;
    const int nt   = (tid >> 9) & 15;
    const int kt   = (tid >> 13) & 7;
    const int l    = tid >> 16;
    const float* W = (l == 0) ? W1 : (l == 1) ? W2 : W3;
    const int k = kt * 32 + (lane >> 4) * 8 + j;
    const int n = nt * 16 + (lane & 15);
    const float w = W[k * 256 + n];
    const __bf16 hi = (__bf16)w;
    const __bf16 lo = (__bf16)(w - (float)hi);
    const size_t base = ((size_t)((l * 8 + kt) * 16 + nt) * 2) * 512 + lane * 8 + j;
    wsw[base]       = hi;
    wsw[base + 512] = lo;
}

// rows: row = state*8 + m  (state 0=H, 1..3=t_k, 4..6=r_k), rows 56..63 zero pad
// LDS: A-frags (Ahi 32KB | Alo 32KB) ALIASED with zbuf (66.5KB); red2 separate.
__global__ __launch_bounds__(256, 2)
void pinn_mfma(const float* __restrict__ X,
               const float* __restrict__ W0, const float* __restrict__ b0,
               const float* __restrict__ b1, const float* __restrict__ b2,
               const float* __restrict__ b3,
               const float* __restrict__ W4, const float* __restrict__ b4,
               const float* __restrict__ lb, const float* __restrict__ ub,
               const __bf16* __restrict__ wsw,
               float* __restrict__ out, int N)
{
    __shared__ __attribute__((aligned(16))) char  smem[64 * ZSTR * 4];  // 66560 B
    __shared__ __attribute__((aligned(16))) float red2[2 * 7 * 256];    // 14336 B
    bf16x8_a* AhiV = (bf16x8_a*)smem;             // vec idx = (kt*4+mt)*64 + lane
    bf16x8_a* AloV = (bf16x8_a*)(smem + 32768);
    f32_a*    zbuf = (f32_a*)smem;                // [row][col], stride ZSTR

    const int t  = threadIdx.x;
    const int s0 = blockIdx.x * MSAMP;
    const int jg = t >> 3;      // unit group: units jg*8 .. jg*8+7
    const int m  = t & 7;       // sample within block
    const int kt0 = jg >> 2, lq0 = jg & 3;   // A-frag coords for this unit group

    // pad-row zeroing coords (rows 56..63 live in mt=3, row&15 in 8..15)
    const int vidz = ((t >> 5) * 4 + 3) * 64 + ((t >> 3) & 3) * 16 + 8 + (t & 7);
    const bf16x8 zvec = {};

    float lbv[3], cv[3];
    #pragma unroll
    for (int k = 0; k < 3; ++k) { lbv[k] = lb[k]; cv[k] = 2.0f / (ub[k] - lbv[k]); }

    // ---------------- layer 0: inputs -> first hidden states (A frags) ----------------
    {
        const int n = s0 + m;
        float x0 = 0.f, x1 = 0.f, x2 = 0.f;
        if (n < N) { x0 = X[n*3+0]; x1 = X[n*3+1]; x2 = X[n*3+2]; }
        const float h0 = cv[0]*(x0 - lbv[0]) - 1.0f;
        const float h1 = cv[1]*(x1 - lbv[1]) - 1.0f;
        const float h2 = cv[2]*(x2 - lbv[2]) - 1.0f;

        float w0v[8], w1v[8], w2v[8], bv[8];
        *(f32x4*)&w0v[0] = *(const f32x4*)&W0[0*256 + jg*8];
        *(f32x4*)&w0v[4] = *(const f32x4*)&W0[0*256 + jg*8 + 4];
        *(f32x4*)&w1v[0] = *(const f32x4*)&W0[1*256 + jg*8];
        *(f32x4*)&w1v[4] = *(const f32x4*)&W0[1*256 + jg*8 + 4];
        *(f32x4*)&w2v[0] = *(const f32x4*)&W0[2*256 + jg*8];
        *(f32x4*)&w2v[4] = *(const f32x4*)&W0[2*256 + jg*8 + 4];
        *(f32x4*)&bv[0]  = *(const f32x4*)&b0[jg*8];
        *(f32x4*)&bv[4]  = *(const f32x4*)&b0[jg*8 + 4];

        float st[7][8];
        #pragma unroll
        for (int jj = 0; jj < 8; ++jj) {
            const float zH  = h0*w0v[jj] + h1*w1v[jj] + h2*w2v[jj] + bv[jj];
            const float zt0 = cv[0]*w0v[jj];
            const float zt1 = cv[1]*w1v[jj];
            const float zt2 = cv[2]*w2v[jj];
            const float h   = tanhf(zH);
            const float dd  = 1.0f - h*h;
            const float q   = -2.0f * h * (zt0 + zt1 + zt2);
            st[0][jj] = h;
            st[1][jj] = dd * zt0; st[2][jj] = dd * zt1; st[3][jj] = dd * zt2;
            st[4][jj] = dd * (q*zt0); st[5][jj] = dd * (q*zt1); st[6][jj] = dd * (q*zt2);
        }
        #pragma unroll
        for (int s = 0; s < 7; ++s) {
            const int row = s*8 + m;
            const int vid = (kt0*4 + (row>>4))*64 + lq0*16 + (row & 15);
            bf16x8 vh, vl;
            #pragma unroll
            for (int jj = 0; jj < 8; ++jj) {
                vh[jj] = (__bf16)st[s][jj];
                vl[jj] = (__bf16)(st[s][jj] - (float)vh[jj]);
            }
            AhiV[vid] = vh;
            AloV[vid] = vl;
        }
        AhiV[vidz] = zvec;     // zero pad rows 56..63
        AloV[vidz] = zvec;
    }
    __syncthreads();

    // ---------------- hidden layers: GEMM (MFMA) + coupling ----------------
    const int wv = t >> 6, lane = t & 63;

    #pragma unroll 1
    for (int l = 0; l < 3; ++l) {
        const __bf16* __restrict__ Wb = wsw + (size_t)l * 131072;

        f32x4 acc[4][4];   // [mt][ntl]
        #pragma unroll
        for (int a = 0; a < 4; ++a)
            #pragma unroll
            for (int b = 0; b < 4; ++b) acc[a][b] = (f32x4){0.f, 0.f, 0.f, 0.f};

        #pragma unroll
        for (int kt = 0; kt < 8; ++kt) {
            bf16x8 ah[4], al[4];
            #pragma unroll
            for (int mt = 0; mt < 4; ++mt) {
                const int vid = (kt*4 + mt)*64 + lane;
                ah[mt] = AhiV[vid];
                al[mt] = AloV[vid];
            }
            #pragma unroll
            for (int ntl = 0; ntl < 4; ++ntl) {
                const int nt = wv*4 + ntl;
                const bf16x8 bh = *(const bf16x8*)&Wb[(size_t)((kt*16 + nt)*2 + 0)*512 + lane*8];
                const bf16x8 bl_= *(const bf16x8*)&Wb[(size_t)((kt*16 + nt)*2 + 1)*512 + lane*8];
                #pragma unroll
                for (int mt = 0; mt < 4; ++mt) {
                    f32x4 c = acc[mt][ntl];
                    c = __builtin_amdgcn_mfma_f32_16x16x32_bf16(al[mt], bh,  c, 0, 0, 0);
                    c = __builtin_amdgcn_mfma_f32_16x16x32_bf16(ah[mt], bl_, c, 0, 0, 0);
                    c = __builtin_amdgcn_mfma_f32_16x16x32_bf16(ah[mt], bh,  c, 0, 0, 0);
                    acc[mt][ntl] = c;
                }
            }
        }
        __syncthreads();   // b1: all A-frag reads complete; zbuf may now clobber A

        // C frags -> zbuf; C: row=mt*16+(lane>>4)*4+reg, col=nt*16+(lane&15)
        #pragma unroll
        for (int mt = 0; mt < 4; ++mt) {
            const int row0 = mt*16 + (lane >> 4)*4;
            #pragma unroll
            for (int ntl = 0; ntl < 4; ++ntl) {
                const int col = (wv*4 + ntl)*16 + (lane & 15);
                #pragma unroll
                for (int reg = 0; reg < 4; ++reg)
                    zbuf[(row0 + reg)*ZSTR + col] = acc[mt][ntl][reg];
            }
        }
        __syncthreads();   // b2: zbuf fully written

        // coupling: thread owns (unit group jg, sample m)
        {
            const float* __restrict__ bb = (l == 0) ? b1 : (l == 1) ? b2 : b3;
            float bvv[8];
            *(f32x4*)&bvv[0] = *(const f32x4*)&bb[jg*8];
            *(f32x4*)&bvv[4] = *(const f32x4*)&bb[jg*8 + 4];

            float z[7][8];
            #pragma unroll
            for (int s = 0; s < 7; ++s) {
                *(f32x4*)&z[s][0] = (f32x4)(*(const f32x4_a*)&zbuf[(s*8 + m)*ZSTR + jg*8]);
                *(f32x4*)&z[s][4] = (f32x4)(*(const f32x4_a*)&zbuf[(s*8 + m)*ZSTR + jg*8 + 4]);
            }
            float stt[7][8];
            #pragma unroll
            for (int jj = 0; jj < 8; ++jj) {
                const float zH  = z[0][jj] + bvv[jj];
                const float zt0 = z[1][jj], zt1 = z[2][jj], zt2 = z[3][jj];
                const float zr0 = z[4][jj], zr1 = z[5][jj], zr2 = z[6][jj];
                const float h   = tanhf(zH);
                const float dd  = 1.0f - h*h;
                const float q   = -2.0f * h * (zt0 + zt1 + zt2);
                stt[0][jj] = h;
                stt[1][jj] = dd * zt0; stt[2][jj] = dd * zt1; stt[3][jj] = dd * zt2;
                stt[4][jj] = dd * (zr0 + q*zt0);
                stt[5][jj] = dd * (zr1 + q*zt1);
                stt[6][jj] = dd * (zr2 + q*zt2);
            }

            if (l < 2) {
                __syncthreads();   // b3: all z reads complete; A-frags may clobber zbuf
                #pragma unroll
                for (int s = 0; s < 7; ++s) {
                    const int row = s*8 + m;
                    const int vid = (kt0*4 + (row>>4))*64 + lq0*16 + (row & 15);
                    bf16x8 vh, vl;
                    #pragma unroll
                    for (int jj = 0; jj < 8; ++jj) {
                        vh[jj] = (__bf16)stt[s][jj];
                        vl[jj] = (__bf16)(stt[s][jj] - (float)vh[jj]);
                    }
                    AhiV[vid] = vh;
                    AloV[vid] = vl;
                }
                AhiV[vidz] = zvec;   // re-zero pad rows (zbuf clobbered them)
                AloV[vidz] = zvec;
                __syncthreads();     // b4: A-frags ready for next GEMM
            } else {
                // final layer fused here: contract stt with this thread's W4 slice,
                // partials go to red2 (separate buffer, no aliasing, no barrier needed)
                float w4r[16];
                #pragma unroll
                for (int q4 = 0; q4 < 4; ++q4)
                    *(f32x4*)&w4r[q4*4] = *(const f32x4*)&W4[jg*16 + q4*4];
                #pragma unroll
                for (int s = 0; s < 7; ++s) {
                    float p0 = 0.f, p1 = 0.f;
                    #pragma unroll
                    for (int jj = 0; jj < 8; ++jj) {
                        p0 += stt[s][jj] * w4r[jj*2 + 0];
                        p1 += stt[s][jj] * w4r[jj*2 + 1];
                    }
                    red2[(0*7 + s)*256 + t] = p0;   // = ... + jg*8 + m
                    red2[(1*7 + s)*256 + t] = p1;
                }
                __syncthreads();     // red2 fully written
            }
        }
    }

    // ---------------- output reduction (56 rows x 2 outputs, 32 partials each) ----------------
    if (t < 112) {
        const int i = t & 1, r = t >> 1;   // r = s*8 + m, 0..55
        const int s = r >> 3, mm = r & 7;
        const float* base = &red2[(i*7 + s)*256 + mm];
        float v = 0.f;
        #pragma unroll
        for (int g = 0; g < 32; ++g) v += base[g*8];
        const int n = s0 + mm;
        if (n < N) {
            const size_t N2 = (size_t)N * 2, N3 = (size_t)N * 3;
            if (s == 0)      out[(size_t)n*2 + i] = v + b4[i];
            else if (s <= 3) out[N2 + (size_t)i*N3 + (size_t)n*3 + (s-1)] = v;
            else             out[N2 + 2*N3 + (size_t)i*N3 + (size_t)n*3 + (s-4)] = v;
        }
    }
}

extern "C" void kernel_launch(void* const* d_in, const int* in_sizes, int n_in,
                              void* d_out, int out_size, void* d_ws, size_t ws_size,
                              hipStream_t stream) {
    const float* X  = (const float*)d_in[0];
    const float* W0 = (const float*)d_in[1];
    const float* b0 = (const float*)d_in[2];
    const float* W1 = (const float*)d_in[3];
    const float* b1 = (const float*)d_in[4];
    const float* W2 = (const float*)d_in[5];
    const float* b2 = (const float*)d_in[6];
    const float* W3 = (const float*)d_in[7];
    const float* b3 = (const float*)d_in[8];
    const float* W4 = (const float*)d_in[9];
    const float* b4 = (const float*)d_in[10];
    const float* lb = (const float*)d_in[11];
    const float* ub = (const float*)d_in[12];
    float* out = (float*)d_out;
    __bf16* wsw = (__bf16*)d_ws;   // needs 768 KB

    const int N = in_sizes[0] / 3;

    prep_w<<<768, 256, 0, stream>>>(W1, W2, W3, wsw);

    const int grid = (N + MSAMP - 1) / MSAMP;
    pinn_mfma<<<grid, 256, 0, stream>>>(X, W0, b0, b1, b2, b3, W4, b4, lb, ub,
                                        wsw, out, N);
}

// Round 5
// 325.093 us; speedup vs baseline: 8.2698x; 1.0246x over previous
//
#include <hip/hip_runtime.h>
#include <math.h>

typedef __bf16 bf16x8 __attribute__((ext_vector_type(8)));
typedef float  f32x4  __attribute__((ext_vector_type(4)));
// may_alias views for the unioned LDS region (A-frags <-> per-wave zbuf)
typedef bf16x8 bf16x8_a __attribute__((may_alias));
typedef f32x4  f32x4_a  __attribute__((may_alias));
typedef float  f32_a    __attribute__((may_alias));

#define MSAMP 8       // samples per block

// W swizzle (bf16 elems): off(l,kt,nt,split,lane,j) =
//   (((l*8+kt)*16+nt)*2+split)*512 + lane*8 + j      ; per-l stride 131072 elems
// One B-fragment (16x16x32): lane holds B[k=kt*32+(lane>>4)*8+j][n=nt*16+(lane&15)]
__global__ void prep_w(const float* __restrict__ W1, const float* __restrict__ W2,
                       const float* __restrict__ W3, __bf16* __restrict__ wsw) {
    const int tid = blockIdx.x * 256 + threadIdx.x;      // 3*8*16*64*8 = 196608
    if (tid >= 3 * 8 * 16 * 64 * 8) return;
    const int j    = tid & 7;
    const int lane = (tid >> 3) & 63;
    const int nt   = (tid >> 9) & 15;
    const int kt   = (tid >> 13) & 7;
    const int l    = tid >> 16;
    const float* W = (l == 0) ? W1 : (l == 1) ? W2 : W3;
    const int k = kt * 32 + (lane >> 4) * 8 + j;
    const int n = nt * 16 + (lane & 15);
    const float w = W[k * 256 + n];
    const __bf16 hi = (__bf16)w;
    const __bf16 lo = (__bf16)(w - (float)hi);
    const size_t base = ((size_t)((l * 8 + kt) * 16 + nt) * 2) * 512 + lane * 8 + j;
    wsw[base]       = hi;
    wsw[base + 512] = lo;
}

// rows: row = state*8 + m  (state 0=H, 1..3=t_k, 4..6=r_k), rows 56..63 zero pad.
// A-frags: Ahi (32KB) | Alo (32KB). Wave wv's kt-slices {2wv,2wv+1} of hi+lo
// double as its PRIVATE 16KB zbuf between the post-GEMM barrier and its A-rewrite.
// zbuf word-index: rows 0..31 in hi region, 32..63 in lo region, stride 64 floats,
// col-block swizzle (cb+row)&7 to spread banks.
__global__ __launch_bounds__(256, 2)
void pinn_mfma(const float* __restrict__ X,
               const float* __restrict__ W0, const float* __restrict__ b0,
               const float* __restrict__ b1, const float* __restrict__ b2,
               const float* __restrict__ b3,
               const float* __restrict__ W4, const float* __restrict__ b4,
               const float* __restrict__ lb, const float* __restrict__ ub,
               const __bf16* __restrict__ wsw,
               float* __restrict__ out, int N)
{
    __shared__ __attribute__((aligned(16))) char  smem[65536];       // Ahi|Alo
    __shared__ __attribute__((aligned(16))) float red2[2 * 7 * 256]; // 14336 B
    bf16x8_a* AhiV = (bf16x8_a*)smem;             // vec idx = (kt*4+mt)*64 + lane
    bf16x8_a* AloV = (bf16x8_a*)(smem + 32768);
    f32_a*    zb   = (f32_a*)smem;                // per-wave zbuf view

    const int t    = threadIdx.x;
    const int s0   = blockIdx.x * MSAMP;
    const int wv   = t >> 6, lane = t & 63;
    const int q    = lane >> 4, c = lane & 15;    // C-frag coords
    const int jgl  = lane >> 3, m = lane & 7;     // coupling task (unit grp, sample)
    const int jg   = wv * 8 + jgl;                // global unit group 0..31
    const int kt0  = jg >> 2, lq0 = jg & 3;       // A-frag coords for jg

    // prologue pad-zero mapping (all 8 kt, by 256 threads)
    const int vidz0 = ((t >> 5) * 4 + 3) * 64 + ((t >> 3) & 3) * 16 + 8 + (t & 7);
    // per-wave pad-zero mapping (wave's own 2 kt slices, by 64 lanes)
    const int vidzw = (((wv * 2 + (lane >> 5)) * 4 + 3) * 64) + (((lane >> 3) & 3) * 16) + 8 + (lane & 7);
    const bf16x8 zvec = {};

    float lbv[3], cv[3];
    #pragma unroll
    for (int k = 0; k < 3; ++k) { lbv[k] = lb[k]; cv[k] = 2.0f / (ub[k] - lbv[k]); }

    // ---------------- layer 0: inputs -> first hidden states (A frags) ----------------
    {
        const int jg0 = t >> 3, m0 = t & 7;       // prologue task mapping (global)
        const int n = s0 + m0;
        float x0 = 0.f, x1 = 0.f, x2 = 0.f;
        if (n < N) { x0 = X[n*3+0]; x1 = X[n*3+1]; x2 = X[n*3+2]; }
        const float h0 = cv[0]*(x0 - lbv[0]) - 1.0f;
        const float h1 = cv[1]*(x1 - lbv[1]) - 1.0f;
        const float h2 = cv[2]*(x2 - lbv[2]) - 1.0f;

        float w0v[8], w1v[8], w2v[8], bv[8];
        *(f32x4*)&w0v[0] = *(const f32x4*)&W0[0*256 + jg0*8];
        *(f32x4*)&w0v[4] = *(const f32x4*)&W0[0*256 + jg0*8 + 4];
        *(f32x4*)&w1v[0] = *(const f32x4*)&W0[1*256 + jg0*8];
        *(f32x4*)&w1v[4] = *(const f32x4*)&W0[1*256 + jg0*8 + 4];
        *(f32x4*)&w2v[0] = *(const f32x4*)&W0[2*256 + jg0*8];
        *(f32x4*)&w2v[4] = *(const f32x4*)&W0[2*256 + jg0*8 + 4];
        *(f32x4*)&bv[0]  = *(const f32x4*)&b0[jg0*8];
        *(f32x4*)&bv[4]  = *(const f32x4*)&b0[jg0*8 + 4];

        float st[7][8];
        #pragma unroll
        for (int jj = 0; jj < 8; ++jj) {
            const float zH  = h0*w0v[jj] + h1*w1v[jj] + h2*w2v[jj] + bv[jj];
            const float zt0 = cv[0]*w0v[jj];
            const float zt1 = cv[1]*w1v[jj];
            const float zt2 = cv[2]*w2v[jj];
            const float h   = tanhf(zH);
            const float dd  = 1.0f - h*h;
            const float qq  = -2.0f * h * (zt0 + zt1 + zt2);
            st[0][jj] = h;
            st[1][jj] = dd * zt0; st[2][jj] = dd * zt1; st[3][jj] = dd * zt2;
            st[4][jj] = dd * (qq*zt0); st[5][jj] = dd * (qq*zt1); st[6][jj] = dd * (qq*zt2);
        }
        const int k0a = jg0 >> 2, l0a = jg0 & 3;
        #pragma unroll
        for (int s = 0; s < 7; ++s) {
            const int row = s*8 + m0;
            const int vid = (k0a*4 + (row>>4))*64 + l0a*16 + (row & 15);
            bf16x8 vh, vl;
            #pragma unroll
            for (int jj = 0; jj < 8; ++jj) {
                vh[jj] = (__bf16)st[s][jj];
                vl[jj] = (__bf16)(st[s][jj] - (float)vh[jj]);
            }
            AhiV[vid] = vh;
            AloV[vid] = vl;
        }
        AhiV[vidz0] = zvec;     // zero pad rows 56..63
        AloV[vidz0] = zvec;
    }
    __syncthreads();

    // ---------------- hidden layers: GEMM (MFMA) + wave-local coupling ----------------
    #pragma unroll 1
    for (int l = 0; l < 3; ++l) {
        const __bf16* __restrict__ Wb = wsw + (size_t)l * 131072;

        f32x4 acc[4][4];   // [mt][ntl]
        #pragma unroll
        for (int a = 0; a < 4; ++a)
            #pragma unroll
            for (int b = 0; b < 4; ++b) acc[a][b] = (f32x4){0.f, 0.f, 0.f, 0.f};

        #pragma unroll
        for (int kt = 0; kt < 8; ++kt) {
            bf16x8 ah[4], al[4];
            #pragma unroll
            for (int mt = 0; mt < 4; ++mt) {
                const int vid = (kt*4 + mt)*64 + lane;
                ah[mt] = AhiV[vid];
                al[mt] = AloV[vid];
            }
            #pragma unroll
            for (int ntl = 0; ntl < 4; ++ntl) {
                const int nt = wv*4 + ntl;
                const bf16x8 bh = *(const bf16x8*)&Wb[(size_t)((kt*16 + nt)*2 + 0)*512 + lane*8];
                const bf16x8 bl_= *(const bf16x8*)&Wb[(size_t)((kt*16 + nt)*2 + 1)*512 + lane*8];
                #pragma unroll
                for (int mt = 0; mt < 4; ++mt) {
                    f32x4 cc2 = acc[mt][ntl];
                    cc2 = __builtin_amdgcn_mfma_f32_16x16x32_bf16(al[mt], bh,  cc2, 0, 0, 0);
                    cc2 = __builtin_amdgcn_mfma_f32_16x16x32_bf16(ah[mt], bl_, cc2, 0, 0, 0);
                    cc2 = __builtin_amdgcn_mfma_f32_16x16x32_bf16(ah[mt], bh,  cc2, 0, 0, 0);
                    acc[mt][ntl] = cc2;
                }
            }
        }
        __syncthreads();   // b1: ALL waves' A-frag reads complete; wave-local zbuf may clobber own slices

        // C frags -> wave-local zbuf. C: row=mt*16+q*4+reg, within-wave col cw=ntl*16+c
        // zbuf word = wv*2048 + (row&31)*64 + (row>>5)*8192 + ((cw>>3 + row)&7)*8 + (cw&7)
        #pragma unroll
        for (int mt = 0; mt < 4; ++mt) {
            #pragma unroll
            for (int reg = 0; reg < 4; ++reg) {
                const int row  = mt*16 + q*4 + reg;
                const int base = wv*2048 + (row & 31)*64 + (row >> 5)*8192;
                #pragma unroll
                for (int ntl = 0; ntl < 4; ++ntl) {
                    const int cw = ntl*16 + c;
                    zb[base + (((cw>>3) + row)&7)*8 + (cw&7)] = acc[mt][ntl][reg];
                }
            }
        }
        // wave-level sync: same-wave LDS RAW needs only lgkmcnt drain, no s_barrier
        asm volatile("s_waitcnt lgkmcnt(0)" ::: "memory");

        // coupling: lane owns (jg = wv*8+jgl, sample m); reads cols jg*8..+7
        {
            const float* __restrict__ bb = (l == 0) ? b1 : (l == 1) ? b2 : b3;
            float bvv[8];
            *(f32x4*)&bvv[0] = *(const f32x4*)&bb[jg*8];
            *(f32x4*)&bvv[4] = *(const f32x4*)&bb[jg*8 + 4];

            float z[7][8];
            #pragma unroll
            for (int s = 0; s < 7; ++s) {
                const int row  = s*8 + m;
                const int base = wv*2048 + (row & 31)*64 + (row >> 5)*8192
                               + ((jgl + row)&7)*8;
                *(f32x4*)&z[s][0] = (f32x4)(*(const f32x4_a*)&zb[base]);
                *(f32x4*)&z[s][4] = (f32x4)(*(const f32x4_a*)&zb[base + 4]);
            }
            float stt[7][8];
            #pragma unroll
            for (int jj = 0; jj < 8; ++jj) {
                const float zH  = z[0][jj] + bvv[jj];
                const float zt0 = z[1][jj], zt1 = z[2][jj], zt2 = z[3][jj];
                const float zr0 = z[4][jj], zr1 = z[5][jj], zr2 = z[6][jj];
                const float h   = tanhf(zH);
                const float dd  = 1.0f - h*h;
                const float qq  = -2.0f * h * (zt0 + zt1 + zt2);
                stt[0][jj] = h;
                stt[1][jj] = dd * zt0; stt[2][jj] = dd * zt1; stt[3][jj] = dd * zt2;
                stt[4][jj] = dd * (zr0 + qq*zt0);
                stt[5][jj] = dd * (zr1 + qq*zt1);
                stt[6][jj] = dd * (zr2 + qq*zt2);
            }

            if (l < 2) {
                // write next-layer A-frags into wave's OWN kt slices (data dep on z
                // reads orders these after the reads; pads after the asm barrier)
                #pragma unroll
                for (int s = 0; s < 7; ++s) {
                    const int row = s*8 + m;
                    const int vid = (kt0*4 + (row>>4))*64 + lq0*16 + (row & 15);
                    bf16x8 vh, vl;
                    #pragma unroll
                    for (int jj = 0; jj < 8; ++jj) {
                        vh[jj] = (__bf16)stt[s][jj];
                        vl[jj] = (__bf16)(stt[s][jj] - (float)vh[jj]);
                    }
                    AhiV[vid] = vh;
                    AloV[vid] = vl;
                }
                AhiV[vidzw] = zvec;   // re-zero wave's pad rows 56..63
                AloV[vidzw] = zvec;
                __syncthreads();      // b2: A-frags ready for next GEMM
            } else {
                // fused final layer: contract stt with W4 slice -> red2 partials
                float w4r[16];
                #pragma unroll
                for (int q4 = 0; q4 < 4; ++q4)
                    *(f32x4*)&w4r[q4*4] = *(const f32x4*)&W4[jg*16 + q4*4];
                #pragma unroll
                for (int s = 0; s < 7; ++s) {
                    float p0 = 0.f, p1 = 0.f;
                    #pragma unroll
                    for (int jj = 0; jj < 8; ++jj) {
                        p0 += stt[s][jj] * w4r[jj*2 + 0];
                        p1 += stt[s][jj] * w4r[jj*2 + 1];
                    }
                    red2[(0*7 + s)*256 + jg*8 + m] = p0;
                    red2[(1*7 + s)*256 + jg*8 + m] = p1;
                }
                __syncthreads();      // red2 fully written
            }
        }
    }

    // ---------------- output reduction (56 rows x 2 outputs, 32 partials each) ----------------
    if (t < 112) {
        const int i = t & 1, r = t >> 1;   // r = s*8 + m, 0..55
        const int s = r >> 3, mm = r & 7;
        const float* base = &red2[(i*7 + s)*256 + mm];
        float v = 0.f;
        #pragma unroll
        for (int g = 0; g < 32; ++g) v += base[g*8];
        const int n = s0 + mm;
        if (n < N) {
            const size_t N2 = (size_t)N * 2, N3 = (size_t)N * 3;
            if (s == 0)      out[(size_t)n*2 + i] = v + b4[i];
            else if (s <= 3) out[N2 + (size_t)i*N3 + (size_t)n*3 + (s-1)] = v;
            else             out[N2 + 2*N3 + (size_t)i*N3 + (size_t)n*3 + (s-4)] = v;
        }
    }
}

extern "C" void kernel_launch(void* const* d_in, const int* in_sizes, int n_in,
                              void* d_out, int out_size, void* d_ws, size_t ws_size,
                              hipStream_t stream) {
    const float* X  = (const float*)d_in[0];
    const float* W0 = (const float*)d_in[1];
    const float* b0 = (const float*)d_in[2];
    const float* W1 = (const float*)d_in[3];
    const float* b1 = (const float*)d_in[4];
    const float* W2 = (const float*)d_in[5];
    const float* b2 = (const float*)d_in[6];
    const float* W3 = (const float*)d_in[7];
    const float* b3 = (const float*)d_in[8];
    const float* W4 = (const float*)d_in[9];
    const float* b4 = (const float*)d_in[10];
    const float* lb = (const float*)d_in[11];
    const float* ub = (const float*)d_in[12];
    float* out = (float*)d_out;
    __bf16* wsw = (__bf16*)d_ws;   // needs 768 KB

    const int N = in_sizes[0] / 3;

    prep_w<<<768, 256, 0, stream>>>(W1, W2, W3, wsw);

    const int grid = (N + MSAMP - 1) / MSAMP;
    pinn_mfma<<<grid, 256, 0, stream>>>(X, W0, b0, b1, b2, b3, W4, b4, lb, ub,
                                        wsw, out, N);
}